// Round 1
// baseline (104.077 us; speedup 1.0000x reference)
//
#include <hip/hip_runtime.h>

#define BN 64
#define TN 1024
#define VN 1024
#define UNITSN 512
#define TWO_PI 6.283185307179586476925286766559f

// K1: s[b*1024+tau] = sum_v x[b, tau, v].  One wave (64 lanes) per row of 1024 floats.
__global__ void k_reduce_v(const float* __restrict__ x, float* __restrict__ s) {
    int row  = blockIdx.x * 4 + (threadIdx.x >> 6);   // 4 waves per 256-thread block
    int lane = threadIdx.x & 63;
    const float4* xr = reinterpret_cast<const float4*>(x) + (size_t)row * (VN / 4);
    float acc = 0.f;
#pragma unroll
    for (int i = 0; i < 4; ++i) {
        float4 v = xr[i * 64 + lane];                 // consecutive lanes -> consecutive 16B
        acc += (v.x + v.y) + (v.z + v.w);
    }
#pragma unroll
    for (int off = 32; off > 0; off >>= 1)
        acc += __shfl_down(acc, off, 64);
    if (lane == 0) s[row] = acc;
}

// K2: F[b*512+t] = sum_tau s[b,tau] * e^{-2*pi*i*tau*t/1024}, t in [0,512)
// grid: 64 b * 8 t-chunks = 512 blocks, 256 threads.
// threads = 64 t-values x 4 tau-chunks of 256.
__global__ void k_dft(const float* __restrict__ s, float2* __restrict__ F) {
    __shared__ float s_lds[1024];
    __shared__ float c_lds[1024];   // cos(-2pi k/1024)
    __shared__ float n_lds[1024];   // sin(-2pi k/1024)
    __shared__ float2 part[4][64];

    int b     = blockIdx.x >> 3;
    int tbase = (blockIdx.x & 7) << 6;
    int tid   = threadIdx.x;

    for (int i = tid; i < 1024; i += 256) {
        s_lds[i] = s[b * 1024 + i];
        float ang = (-TWO_PI / 1024.0f) * (float)i;
        float sv, cv;
        sincosf(ang, &sv, &cv);
        c_lds[i] = cv;
        n_lds[i] = sv;
    }
    __syncthreads();

    int tl    = tid & 63;
    int chunk = tid >> 6;
    int t     = tbase + tl;
    int tau0  = chunk * 256;

    float ar = 0.f, ai = 0.f;
    int p = (tau0 * t) & 1023;      // phase index tau*t mod 1024
    for (int tau = tau0; tau < tau0 + 256; ++tau) {
        float sv = s_lds[tau];      // broadcast (free)
        ar = fmaf(sv, c_lds[p], ar);
        ai = fmaf(sv, n_lds[p], ai);
        p = (p + t) & 1023;
    }
    part[chunk][tl] = make_float2(ar, ai);
    __syncthreads();

    if (tid < 64) {
        float2 a0 = part[0][tid], a1 = part[1][tid], a2 = part[2][tid], a3 = part[3][tid];
        F[b * UNITSN + tbase + tid] =
            make_float2((a0.x + a1.x) + (a2.x + a3.x), (a0.y + a1.y) + (a2.y + a3.y));
    }
}

// K3: W[b,t] = (1/2048) * sum_k (Br[b,k] + i*Bi[b,k]) * F[k,t]
// (folds: zi = 0.5*Bm@U, U = F/1024^2, out scale *1024  ->  0.5*1024/1024^2 = 1/2048)
__global__ void k_matmul(const float* __restrict__ Br, const float* __restrict__ Bi,
                         const float2* __restrict__ F, float2* __restrict__ W) {
    int idx = blockIdx.x * blockDim.x + threadIdx.x;  // 64*512 threads
    int b = idx >> 9;
    int t = idx & 511;
    float wr = 0.f, wi = 0.f;
#pragma unroll 8
    for (int k = 0; k < 64; ++k) {
        float br = Br[b * 64 + k];
        float bi = Bi[b * 64 + k];
        float2 f = F[k * UNITSN + t];                 // consecutive lanes -> consecutive t
        wr += br * f.x - bi * f.y;
        wi += br * f.y + bi * f.x;
    }
    const float coef = 1.0f / 2048.0f;
    W[idx] = make_float2(wr * coef, wi * coef);
}

// K4: out[b][j][t][{re,im}] = W[b,t] + (t+j-511 >= 0 ? W[b, t+j-511] : 0)
// One thread writes 2 consecutive t's as a float4.
__global__ void k_expand(const float2* __restrict__ W, float4* __restrict__ out) {
    int idx = blockIdx.x * 256 + threadIdx.x;         // 64*512*256 total
    int t2 = (idx & 255) * 2;
    int j  = (idx >> 8) & 511;
    int b  = idx >> 17;
    const float2* Wb = W + b * UNITSN;
    float2 w0 = Wb[t2];
    float2 w1 = Wb[t2 + 1];
    int k0 = t2 + j - 511;
    float2 z0 = (k0 >= 0)     ? Wb[k0]     : make_float2(0.f, 0.f);
    float2 z1 = (k0 + 1 >= 0) ? Wb[k0 + 1] : make_float2(0.f, 0.f);
    out[idx] = make_float4(w0.x + z0.x, w0.y + z0.y, w1.x + z1.x, w1.y + z1.y);
}

extern "C" void kernel_launch(void* const* d_in, const int* in_sizes, int n_in,
                              void* d_out, int out_size, void* d_ws, size_t ws_size,
                              hipStream_t stream) {
    const float* x  = (const float*)d_in[0];
    // d_in[1], d_in[2] (A_r, A_i) are provably unused: the shift-register state's
    // column 0 stays zero for all 512 scan steps.
    const float* Br = (const float*)d_in[3];
    const float* Bi = (const float*)d_in[4];

    char* ws = (char*)d_ws;
    float*  s = (float*)ws;                       // 64*1024 f32   = 256 KB
    float2* F = (float2*)(ws + (64 * 1024 * 4));  // 64*512 cplx   = 256 KB
    float2* W = (float2*)(ws + (64 * 1024 * 4) + (64 * 512 * 8)); // 256 KB

    // K1: 65536 rows, 4 rows/block
    k_reduce_v<<<BN * TN / 4, 256, 0, stream>>>(x, s);
    // K2: 64 b * 8 t-chunks
    k_dft<<<BN * 8, 256, 0, stream>>>(s, F);
    // K3: 64*512 threads
    k_matmul<<<(BN * UNITSN) / 256, 256, 0, stream>>>(Br, Bi, F, W);
    // K4: 64*512*256 threads
    k_expand<<<(BN * UNITSN * (UNITSN / 2)) / 256, 256, 0, stream>>>(W, (float4*)d_out);
}

// Round 2
// 101.707 us; speedup vs baseline: 1.0233x; 1.0233x over previous
//
#include <hip/hip_runtime.h>

#define BN 64
#define TN 1024
#define VN 1024
#define UNITSN 512
#define TWO_PI 6.283185307179586476925286766559f

// K1: s[b*1024+tau] = sum_v x[b, tau, v].  One wave (64 lanes) per row of 1024 floats.
__global__ void k_reduce_v(const float* __restrict__ x, float* __restrict__ s) {
    int row  = blockIdx.x * 4 + (threadIdx.x >> 6);   // 4 waves per 256-thread block
    int lane = threadIdx.x & 63;
    const float4* xr = reinterpret_cast<const float4*>(x) + (size_t)row * (VN / 4);
    float acc = 0.f;
#pragma unroll
    for (int i = 0; i < 4; ++i) {
        float4 v = xr[i * 64 + lane];                 // consecutive lanes -> consecutive 16B
        acc += (v.x + v.y) + (v.z + v.w);
    }
#pragma unroll
    for (int off = 32; off > 0; off >>= 1)
        acc += __shfl_down(acc, off, 64);
    if (lane == 0) s[row] = acc;
}

// K2: F[b*512+t] = sum_tau s[b,tau] * e^{-2*pi*i*tau*t/1024}, t in [0,512)
// One WAVE per (b,t). Lane l covers tau = l, l+64, ..., l+960 (16 steps).
// Twiddle carried in registers via complex rotation by e^{-2*pi*i*64*t/1024};
// start/step computed once with sincosf (angles pre-reduced mod 2*pi).
// No LDS at all; s row reads are coalesced and L1/L2-resident.
__global__ void k_dft(const float* __restrict__ s, float2* __restrict__ F) {
    int w    = (blockIdx.x * blockDim.x + threadIdx.x) >> 6;  // global wave id
    int lane = threadIdx.x & 63;
    int b    = w >> 9;
    int t    = w & 511;
    const float* sb = s + b * TN;

    int p0 = (lane * t) & 1023;        // start phase index (mod 1024)
    int ps = (64 * t) & 1023;          // step phase index
    float cr, ci, c1, s1;
    sincosf((-TWO_PI / 1024.0f) * (float)p0, &ci, &cr);  // (cos,sin) of start
    sincosf((-TWO_PI / 1024.0f) * (float)ps, &s1, &c1);  // (cos,sin) of step

    float ar = 0.f, ai = 0.f;
#pragma unroll
    for (int i = 0; i < 16; ++i) {
        float sv = sb[lane + 64 * i];
        ar = fmaf(sv, cr, ar);
        ai = fmaf(sv, ci, ai);
        float nr = cr * c1 - ci * s1;  // rotate twiddle by step
        float nc = cr * s1 + ci * c1;
        cr = nr; ci = nc;
    }
#pragma unroll
    for (int off = 32; off > 0; off >>= 1) {
        ar += __shfl_xor(ar, off, 64);
        ai += __shfl_xor(ai, off, 64);
    }
    if (lane == 0) F[b * UNITSN + t] = make_float2(ar, ai);
}

// K3: W[b,t] = (1/2048) * sum_k (Br[b,k] + i*Bi[b,k]) * F[k,t]
// (folds: zi = 0.5*Bm@U, U = F/1024^2, out scale *1024  ->  0.5*1024/1024^2 = 1/2048)
__global__ void k_matmul(const float* __restrict__ Br, const float* __restrict__ Bi,
                         const float2* __restrict__ F, float2* __restrict__ W) {
    int idx = blockIdx.x * blockDim.x + threadIdx.x;  // 64*512 threads
    int b = idx >> 9;
    int t = idx & 511;
    float wr = 0.f, wi = 0.f;
#pragma unroll 16
    for (int k = 0; k < 64; ++k) {
        float br = Br[b * 64 + k];
        float bi = Bi[b * 64 + k];
        float2 f = F[k * UNITSN + t];                 // consecutive lanes -> consecutive t
        wr += br * f.x - bi * f.y;
        wi += br * f.y + bi * f.x;
    }
    const float coef = 1.0f / 2048.0f;
    W[idx] = make_float2(wr * coef, wi * coef);
}

// K4: out[b][j][t][{re,im}] = W[b,t] + (t+j-511 >= 0 ? W[b, t+j-511] : 0)
// One thread writes 2 consecutive t's as a float4.
__global__ void k_expand(const float2* __restrict__ W, float4* __restrict__ out) {
    int idx = blockIdx.x * 256 + threadIdx.x;         // 64*512*256 total
    int t2 = (idx & 255) * 2;
    int j  = (idx >> 8) & 511;
    int b  = idx >> 17;
    const float2* Wb = W + b * UNITSN;
    float4 w01 = *reinterpret_cast<const float4*>(Wb + t2);  // W[t2], W[t2+1] (16B-aligned)
    int k0 = t2 + j - 511;
    float2 z0 = (k0 >= 0)     ? Wb[k0]     : make_float2(0.f, 0.f);
    float2 z1 = (k0 + 1 >= 0) ? Wb[k0 + 1] : make_float2(0.f, 0.f);
    out[idx] = make_float4(w01.x + z0.x, w01.y + z0.y, w01.z + z1.x, w01.w + z1.y);
}

extern "C" void kernel_launch(void* const* d_in, const int* in_sizes, int n_in,
                              void* d_out, int out_size, void* d_ws, size_t ws_size,
                              hipStream_t stream) {
    const float* x  = (const float*)d_in[0];
    // d_in[1], d_in[2] (A_r, A_i) are provably unused: the shift-register state's
    // column 0 stays zero for all 512 scan steps.
    const float* Br = (const float*)d_in[3];
    const float* Bi = (const float*)d_in[4];

    char* ws = (char*)d_ws;
    float*  s = (float*)ws;                       // 64*1024 f32   = 256 KB
    float2* F = (float2*)(ws + (64 * 1024 * 4));  // 64*512 cplx   = 256 KB
    float2* W = (float2*)(ws + (64 * 1024 * 4) + (64 * 512 * 8)); // 256 KB

    // K1: 65536 rows, 4 rows/block
    k_reduce_v<<<BN * TN / 4, 256, 0, stream>>>(x, s);
    // K2: 64 b * 512 t waves, 4 waves/block
    k_dft<<<(BN * UNITSN) / 4, 256, 0, stream>>>(s, F);
    // K3: 64*512 threads
    k_matmul<<<(BN * UNITSN) / 256, 256, 0, stream>>>(Br, Bi, F, W);
    // K4: 64*512*256 threads
    k_expand<<<(BN * UNITSN * (UNITSN / 2)) / 256, 256, 0, stream>>>(W, (float4*)d_out);
}